// Round 1
// baseline (737.807 us; speedup 1.0000x reference)
//
#include <hip/hip_runtime.h>

#define D_IN  4096
#define D_OUT 4096
#define RANK  256
#define KCAT  (D_IN + RANK)   // 4352

typedef _Float16 h4 __attribute__((ext_vector_type(4)));
typedef _Float16 h8 __attribute__((ext_vector_type(8)));
typedef float    f4 __attribute__((ext_vector_type(4)));

__device__ __forceinline__ void gload16(const void* g, void* l) {
  __builtin_amdgcn_global_load_lds(
      (const __attribute__((address_space(1))) void*)g,
      (__attribute__((address_space(3))) void*)l, 16, 0, 0);
}

// ---------------- prologue: dequant + pack ----------------

// Wcat[row][0:4096)  = q_values*q_scales ; Wcat[row][4096:4352) = l_values*l_scales
__global__ __launch_bounds__(256) void k_dequant_w(
    const int* __restrict__ qv, const float* __restrict__ qs,
    const int* __restrict__ lv, const float* __restrict__ ls,
    _Float16* __restrict__ W) {
  int row = blockIdx.y;
  int c4 = blockIdx.x * 256 + threadIdx.x;    // quad index, 0..1087
  if (c4 >= KCAT / 4) return;
  int col = c4 * 4;
  int4 v; float s;
  if (col < D_IN) {
    v = *(const int4*)(qv + (size_t)row * D_IN + col);
    s = qs[row * (D_IN / 128) + (col >> 7)];
  } else {
    int lc = col - D_IN;
    v = *(const int4*)(lv + (size_t)row * RANK + lc);
    s = ls[row * (RANK / 128) + (lc >> 7)];
  }
  h4 h;
  h[0] = (_Float16)((float)v.x * s);
  h[1] = (_Float16)((float)v.y * s);
  h[2] = (_Float16)((float)v.z * s);
  h[3] = (_Float16)((float)v.w * s);
  *(h4*)(W + (size_t)row * KCAT + col) = h;
}

__global__ __launch_bounds__(256) void k_dequant_r(
    const int* __restrict__ rv, const float* __restrict__ rs,
    _Float16* __restrict__ R) {
  int row = blockIdx.y;
  int c4 = blockIdx.x * 256 + threadIdx.x;    // 0..1023
  int col = c4 * 4;
  int4 v = *(const int4*)(rv + (size_t)row * D_IN + col);
  float s = rs[row * (D_IN / 128) + (col >> 7)];
  h4 h;
  h[0] = (_Float16)((float)v.x * s);
  h[1] = (_Float16)((float)v.y * s);
  h[2] = (_Float16)((float)v.z * s);
  h[3] = (_Float16)((float)v.w * s);
  *(h4*)(R + (size_t)row * D_IN + col) = h;
}

__global__ __launch_bounds__(256) void k_convert_x(
    const float* __restrict__ x, _Float16* __restrict__ X, int total4) {
  int i = blockIdx.x * 256 + threadIdx.x;
  if (i >= total4) return;
  f4 v = *(const f4*)(x + (size_t)i * 4);
  int row = i >> 10;           // D_IN/4 = 1024 quads per row
  int c4  = i & 1023;
  h4 h;
  h[0] = (_Float16)v[0]; h[1] = (_Float16)v[1];
  h[2] = (_Float16)v[2]; h[3] = (_Float16)v[3];
  *(h4*)(X + (size_t)row * KCAT + c4 * 4) = h;
}

// ---------------- GEMM: C[M][N] = A[M][K] * B[N][K]^T (+bias) ----------------
// m97 structure: BK=32, 4 waves (2x2), global_load_lds width 16, 2 barriers/K-step.
template<int BM, int BN, int MF, int NF, bool OUT_F16, bool ADD_BIAS>
__global__ __launch_bounds__(256) void k_gemm_bt(
    const _Float16* __restrict__ A, int lda,
    const _Float16* __restrict__ B, int ldb,
    void* __restrict__ Cv, int ldc,
    const float* __restrict__ bias,
    int K, int grid_n) {
  constexpr int WM = MF * 16, WN = NF * 16;   // per-wave tile (BM=2*WM, BN=2*WN)
  __shared__ _Float16 As[BM][32];
  __shared__ _Float16 Bs[BN][32];

  // XCD-aware bijective swizzle (grid always a multiple of 8 here)
  int bid = blockIdx.x;
  { int q = gridDim.x >> 3; bid = (bid & 7) * q + (bid >> 3); }
  int bm = bid / grid_n, bn = bid % grid_n;

  int tid  = threadIdx.x;
  int lane = tid & 63, wave = tid >> 6;
  int wr = wave >> 1, wc = wave & 1;

  // staging map: thread t -> row t/4, elem-col (t%4)*8 ; LDS offset = t*16 B (linear)
  int trow = tid >> 2;
  int tcol = (tid & 3) * 8;
  const _Float16* ga = A + (size_t)(bm * BM + trow) * lda + tcol;
  const _Float16* gb = B + (size_t)(bn * BN + trow) * ldb + tcol;

  f4 acc[MF][NF] = {};

  int fr = lane & 15;          // fragment row (M for A, N for B)
  int fk = (lane >> 4) * 8;    // k offset within BK=32

  for (int k0 = 0; k0 < K; k0 += 32) {
#pragma unroll
    for (int p = 0; p < BM / 64; ++p)
      gload16(ga + (size_t)p * 64 * lda + k0, &As[p * 64 + trow][tcol]);
#pragma unroll
    for (int p = 0; p < BN / 64; ++p)
      gload16(gb + (size_t)p * 64 * ldb + k0, &Bs[p * 64 + trow][tcol]);
    __syncthreads();           // compiler emits vmcnt(0) drain here

    h8 a[MF], b[NF];
#pragma unroll
    for (int m = 0; m < MF; ++m)
      a[m] = *(const h8*)&As[wr * WM + m * 16 + fr][fk];
#pragma unroll
    for (int n = 0; n < NF; ++n)
      b[n] = *(const h8*)&Bs[wc * WN + n * 16 + fr][fk];
#pragma unroll
    for (int m = 0; m < MF; ++m)
#pragma unroll
      for (int n = 0; n < NF; ++n)
        acc[m][n] = __builtin_amdgcn_mfma_f32_16x16x32_f16(a[m], b[n], acc[m][n], 0, 0, 0);
    __syncthreads();
  }

  // C/D layout (m89-verified): col = lane&15, row = (lane>>4)*4 + reg
  int cr = (lane >> 4) * 4;
  int cc = lane & 15;
#pragma unroll
  for (int m = 0; m < MF; ++m) {
#pragma unroll
    for (int n = 0; n < NF; ++n) {
      int col = bn * BN + wc * WN + n * 16 + cc;
      float bv = ADD_BIAS ? bias[col] : 0.f;
#pragma unroll
      for (int r = 0; r < 4; ++r) {
        int row = bm * BM + wr * WM + m * 16 + cr + r;
        float val = acc[m][n][r] + bv;
        if (OUT_F16) ((_Float16*)Cv)[(size_t)row * ldc + col] = (_Float16)val;
        else         ((float*)Cv)[(size_t)row * ldc + col]    = val;
      }
    }
  }
}

// ---------------- launch ----------------
extern "C" void kernel_launch(void* const* d_in, const int* in_sizes, int n_in,
                              void* d_out, int out_size, void* d_ws, size_t ws_size,
                              hipStream_t stream) {
  const float* x    = (const float*)d_in[0];
  const int*   qv   = (const int*)d_in[1];
  const float* qs   = (const float*)d_in[2];
  const int*   lv   = (const int*)d_in[3];
  const float* ls   = (const float*)d_in[4];
  const int*   rv   = (const int*)d_in[5];
  const float* rs   = (const float*)d_in[6];
  const float* bias = (const float*)d_in[7];

  int M = in_sizes[0] / D_IN;   // 8192

  char* ws = (char*)d_ws;
  _Float16* Xcat = (_Float16*)ws;                                   // [M][KCAT]
  _Float16* Wcat = (_Float16*)(ws + (size_t)M * KCAT * 2);          // [D_OUT][KCAT]
  _Float16* Rh   = (_Float16*)(ws + (size_t)(M + D_OUT) * KCAT * 2);// [RANK][D_IN]

  k_dequant_w<<<dim3((KCAT / 4 + 255) / 256, D_OUT), 256, 0, stream>>>(qv, qs, lv, ls, Wcat);
  k_dequant_r<<<dim3(D_IN / 4 / 256, RANK), 256, 0, stream>>>(rv, rs, Rh);
  int total4 = M * (D_IN / 4);
  k_convert_x<<<(total4 + 255) / 256, 256, 0, stream>>>(x, Xcat, total4);

  // xr = Xcat[:, :4096] @ Rh^T  -> f16 into Xcat[:, 4096:4352]
  k_gemm_bt<64, 64, 2, 2, true, false><<<(M / 64) * (RANK / 64), 256, 0, stream>>>(
      Xcat, KCAT, Rh, D_IN, (void*)(Xcat + D_IN), KCAT, nullptr, D_IN, RANK / 64);

  // out = Xcat @ Wcat^T + bias   (K = 4352 covers both q and low-rank paths)
  k_gemm_bt<128, 128, 4, 4, false, true><<<(M / 128) * (D_OUT / 128), 256, 0, stream>>>(
      Xcat, KCAT, Wcat, KCAT, d_out, D_OUT, bias, KCAT, D_OUT / 128);
}

// Round 2
// 596.835 us; speedup vs baseline: 1.2362x; 1.2362x over previous
//
#include <hip/hip_runtime.h>

#define D_IN  4096
#define D_OUT 4096
#define RANK  256
#define KCAT  (D_IN + RANK)   // 4352

typedef _Float16 h4 __attribute__((ext_vector_type(4)));
typedef _Float16 h8 __attribute__((ext_vector_type(8)));
typedef float    f4 __attribute__((ext_vector_type(4)));

__device__ __forceinline__ void gload16(const void* g, void* l) {
  __builtin_amdgcn_global_load_lds(
      (const __attribute__((address_space(1))) void*)g,
      (__attribute__((address_space(3))) void*)l, 16, 0, 0);
}

// ---------------- prologue: dequant + pack ----------------

__global__ __launch_bounds__(256) void k_dequant_w(
    const int* __restrict__ qv, const float* __restrict__ qs,
    const int* __restrict__ lv, const float* __restrict__ ls,
    _Float16* __restrict__ W) {
  int row = blockIdx.y;
  int c4 = blockIdx.x * 256 + threadIdx.x;    // quad index, 0..1087
  if (c4 >= KCAT / 4) return;
  int col = c4 * 4;
  int4 v; float s;
  if (col < D_IN) {
    v = *(const int4*)(qv + (size_t)row * D_IN + col);
    s = qs[row * (D_IN / 128) + (col >> 7)];
  } else {
    int lc = col - D_IN;
    v = *(const int4*)(lv + (size_t)row * RANK + lc);
    s = ls[row * (RANK / 128) + (lc >> 7)];
  }
  h4 h;
  h[0] = (_Float16)((float)v.x * s);
  h[1] = (_Float16)((float)v.y * s);
  h[2] = (_Float16)((float)v.z * s);
  h[3] = (_Float16)((float)v.w * s);
  *(h4*)(W + (size_t)row * KCAT + col) = h;
}

__global__ __launch_bounds__(256) void k_dequant_r(
    const int* __restrict__ rv, const float* __restrict__ rs,
    _Float16* __restrict__ R) {
  int row = blockIdx.y;
  int c4 = blockIdx.x * 256 + threadIdx.x;    // 0..1023
  int col = c4 * 4;
  int4 v = *(const int4*)(rv + (size_t)row * D_IN + col);
  float s = rs[row * (D_IN / 128) + (col >> 7)];
  h4 h;
  h[0] = (_Float16)((float)v.x * s);
  h[1] = (_Float16)((float)v.y * s);
  h[2] = (_Float16)((float)v.z * s);
  h[3] = (_Float16)((float)v.w * s);
  *(h4*)(R + (size_t)row * D_IN + col) = h;
}

__global__ __launch_bounds__(256) void k_convert_x(
    const float* __restrict__ x, _Float16* __restrict__ X, int total4) {
  int i = blockIdx.x * 256 + threadIdx.x;
  if (i >= total4) return;
  f4 v = *(const f4*)(x + (size_t)i * 4);
  int row = i >> 10;           // D_IN/4 = 1024 quads per row
  int c4  = i & 1023;
  h4 h;
  h[0] = (_Float16)v[0]; h[1] = (_Float16)v[1];
  h[2] = (_Float16)v[2]; h[3] = (_Float16)v[3];
  *(h4*)(X + (size_t)row * KCAT + c4 * 4) = h;
}

// ---------------- small GEMM (xr path): m97 structure ----------------
template<int BM, int BN, int MF, int NF, bool OUT_F16, bool ADD_BIAS>
__global__ __launch_bounds__(256) void k_gemm_bt(
    const _Float16* __restrict__ A, int lda,
    const _Float16* __restrict__ B, int ldb,
    void* __restrict__ Cv, int ldc,
    const float* __restrict__ bias,
    int K, int grid_n) {
  constexpr int WM = MF * 16, WN = NF * 16;
  __shared__ _Float16 As[BM][32];
  __shared__ _Float16 Bs[BN][32];

  int bid = blockIdx.x;
  { int q = gridDim.x >> 3; bid = (bid & 7) * q + (bid >> 3); }
  int bm = bid / grid_n, bn = bid % grid_n;

  int tid  = threadIdx.x;
  int lane = tid & 63, wave = tid >> 6;
  int wr = wave >> 1, wc = wave & 1;

  int trow = tid >> 2;
  int tcol = (tid & 3) * 8;
  const _Float16* ga = A + (size_t)(bm * BM + trow) * lda + tcol;
  const _Float16* gb = B + (size_t)(bn * BN + trow) * ldb + tcol;

  f4 acc[MF][NF] = {};

  int fr = lane & 15;
  int fk = (lane >> 4) * 8;

  for (int k0 = 0; k0 < K; k0 += 32) {
#pragma unroll
    for (int p = 0; p < BM / 64; ++p)
      gload16(ga + (size_t)p * 64 * lda + k0, &As[p * 64 + trow][tcol]);
#pragma unroll
    for (int p = 0; p < BN / 64; ++p)
      gload16(gb + (size_t)p * 64 * ldb + k0, &Bs[p * 64 + trow][tcol]);
    __syncthreads();

    h8 a[MF], b[NF];
#pragma unroll
    for (int m = 0; m < MF; ++m)
      a[m] = *(const h8*)&As[wr * WM + m * 16 + fr][fk];
#pragma unroll
    for (int n = 0; n < NF; ++n)
      b[n] = *(const h8*)&Bs[wc * WN + n * 16 + fr][fk];
#pragma unroll
    for (int m = 0; m < MF; ++m)
#pragma unroll
      for (int n = 0; n < NF; ++n)
        acc[m][n] = __builtin_amdgcn_mfma_f32_16x16x32_f16(a[m], b[n], acc[m][n], 0, 0, 0);
    __syncthreads();
  }

  int cr = (lane >> 4) * 4;
  int cc = lane & 15;
#pragma unroll
  for (int m = 0; m < MF; ++m) {
#pragma unroll
    for (int n = 0; n < NF; ++n) {
      int col = bn * BN + wc * WN + n * 16 + cc;
      float bv = ADD_BIAS ? bias[col] : 0.f;
#pragma unroll
      for (int r = 0; r < 4; ++r) {
        int row = bm * BM + wr * WM + m * 16 + cr + r;
        float val = acc[m][n][r] + bv;
        if (OUT_F16) ((_Float16*)Cv)[(size_t)row * ldc + col] = (_Float16)val;
        else         ((float*)Cv)[(size_t)row * ldc + col]    = val;
      }
    }
  }
}

// ---------------- main GEMM: 256x256 8-phase (T2+T3+T4+T5) ----------------
// C[M][N] = A[M][K] * B[N][K]^T + bias.  BK=64, 8 waves (2Mx4N), 128 KiB LDS.
// LDS regions per buffer: 0=A-half0(rows 0-127), 1=A-half1, 2=B-half0, 3=B-half1.
// Swizzle: 16B-seg index within a 128B row XORed with (row&7); applied to the
// global SOURCE column on staging (linear LDS dest) and to the ds_read address.
__global__ __launch_bounds__(512, 2) void k_gemm256(
    const _Float16* __restrict__ A, int lda,
    const _Float16* __restrict__ B, int ldb,
    float* __restrict__ C, int ldc,
    const float* __restrict__ bias,
    int K, int grid_n) {
  __shared__ _Float16 smem[2 * 4 * 8192];   // 131072 B

  int bid = blockIdx.x;
  { int q = gridDim.x >> 3; bid = (bid & 7) * q + (bid >> 3); }  // XCD swizzle
  const int bm = bid / grid_n, bn = bid % grid_n;

  const int tid  = threadIdx.x;
  const int lane = tid & 63, wave = tid >> 6;
  const int wr = wave >> 2;          // 0..1  (M half)
  const int wc = wave & 3;           // 0..3  (N quarter)

  const int fr   = lane & 15;        // fragment row
  const int kgrp = lane >> 4;        // 0..3, k-seg within 32-wide k-step
  const int xorv = fr & 7;
  const int seg0 = ((0 | kgrp) ^ xorv) * 8;   // elem offset, ks=0
  const int seg1 = ((4 | kgrp) ^ xorv) * 8;   // elem offset, ks=1

  // staging map: thread -> row tid/8, seg (tid&7)^(row&7); LDS linear tid*16B
  const int srow = tid >> 3;
  const int scol = ((tid & 7) ^ (srow & 7)) * 8;
  const _Float16* gA = A + (size_t)(bm * 256 + srow) * lda + scol;
  const _Float16* gB = B + (size_t)(bn * 256 + srow) * ldb + scol;

  const int NT = K >> 6;             // K-tiles of 64

  f4 acc[8][4] = {};
  h8 a[4][2], b01[2][2], b23[2][2];

  auto stA = [&](int buf, int h, int t) {
    const _Float16* g = gA + (size_t)h * 128 * lda + t * 64;
    _Float16* l = smem + (buf * 4 + h) * 8192 + tid * 8;
    gload16(g, l);
    gload16(g + (size_t)64 * lda, l + 4096);
  };
  auto stB = [&](int buf, int h, int t) {
    const _Float16* g = gB + (size_t)h * 128 * ldb + t * 64;
    _Float16* l = smem + (buf * 4 + 2 + h) * 8192 + tid * 8;
    gload16(g, l);
    gload16(g + (size_t)64 * ldb, l + 4096);
  };

  // prologue: t0 fully; t1's B halves (its A halves issue during t0 p1/p2)
  stA(0, 0, 0); stA(0, 1, 0); stB(0, 0, 0); stB(0, 1, 0);
  if (NT > 1) {
    stB(1, 0, 1); stB(1, 1, 1);
    asm volatile("s_waitcnt vmcnt(4)" ::: "memory");
  } else {
    asm volatile("s_waitcnt vmcnt(0)" ::: "memory");
  }
  __builtin_amdgcn_s_barrier();

  for (int t = 0; t < NT; ++t) {
    const int buf = t & 1, nbuf = buf ^ 1;
    const _Float16* aB = smem + (buf * 4 + wr) * 8192 + fr * 64;
    const _Float16* bB = smem + (buf * 4 + 2 + (wc >> 1)) * 8192
                       + ((wc & 1) * 64 + fr) * 64;

    // ---- phase 1: read A[m0-3] + B[n0-1]; stage (t+1).Ah0; q0 ----
#pragma unroll
    for (int mm = 0; mm < 4; ++mm) {
      a[mm][0] = *(const h8*)(aB + mm * 1024 + seg0);
      a[mm][1] = *(const h8*)(aB + mm * 1024 + seg1);
    }
#pragma unroll
    for (int nn = 0; nn < 2; ++nn) {
      b01[nn][0] = *(const h8*)(bB + nn * 1024 + seg0);
      b01[nn][1] = *(const h8*)(bB + nn * 1024 + seg1);
    }
    if (t + 1 < NT) stA(nbuf, 0, t + 1);
    __builtin_amdgcn_s_barrier();
    asm volatile("s_waitcnt lgkmcnt(0)" ::: "memory");
    __builtin_amdgcn_s_setprio(1);
#pragma unroll
    for (int mm = 0; mm < 4; ++mm)
#pragma unroll
      for (int nn = 0; nn < 2; ++nn) {
        acc[mm][nn] = __builtin_amdgcn_mfma_f32_16x16x32_f16(a[mm][0], b01[nn][0], acc[mm][nn], 0, 0, 0);
        acc[mm][nn] = __builtin_amdgcn_mfma_f32_16x16x32_f16(a[mm][1], b01[nn][1], acc[mm][nn], 0, 0, 0);
      }
    __builtin_amdgcn_s_setprio(0);
    __builtin_amdgcn_s_barrier();

    // ---- phase 2: read B[n2-3]; stage (t+1).Ah1; q1 ----
#pragma unroll
    for (int nn = 0; nn < 2; ++nn) {
      b23[nn][0] = *(const h8*)(bB + (2 + nn) * 1024 + seg0);
      b23[nn][1] = *(const h8*)(bB + (2 + nn) * 1024 + seg1);
    }
    if (t + 1 < NT) stA(nbuf, 1, t + 1);
    __builtin_amdgcn_s_barrier();
    asm volatile("s_waitcnt lgkmcnt(0)" ::: "memory");
    __builtin_amdgcn_s_setprio(1);
#pragma unroll
    for (int mm = 0; mm < 4; ++mm)
#pragma unroll
      for (int nn = 0; nn < 2; ++nn) {
        acc[mm][2 + nn] = __builtin_amdgcn_mfma_f32_16x16x32_f16(a[mm][0], b23[nn][0], acc[mm][2 + nn], 0, 0, 0);
        acc[mm][2 + nn] = __builtin_amdgcn_mfma_f32_16x16x32_f16(a[mm][1], b23[nn][1], acc[mm][2 + nn], 0, 0, 0);
      }
    __builtin_amdgcn_s_setprio(0);
    __builtin_amdgcn_s_barrier();

    // ---- phase 3: read A[m4-7]; stage (t+2).Bh0; q2 ----
#pragma unroll
    for (int mm = 0; mm < 4; ++mm) {
      a[mm][0] = *(const h8*)(aB + (4 + mm) * 1024 + seg0);
      a[mm][1] = *(const h8*)(aB + (4 + mm) * 1024 + seg1);
    }
    if (t + 2 < NT) stB(buf, 0, t + 2);
    __builtin_amdgcn_s_barrier();
    asm volatile("s_waitcnt lgkmcnt(0)" ::: "memory");
    __builtin_amdgcn_s_setprio(1);
#pragma unroll
    for (int mm = 0; mm < 4; ++mm)
#pragma unroll
      for (int nn = 0; nn < 2; ++nn) {
        acc[4 + mm][2 + nn] = __builtin_amdgcn_mfma_f32_16x16x32_f16(a[mm][0], b23[nn][0], acc[4 + mm][2 + nn], 0, 0, 0);
        acc[4 + mm][2 + nn] = __builtin_amdgcn_mfma_f32_16x16x32_f16(a[mm][1], b23[nn][1], acc[4 + mm][2 + nn], 0, 0, 0);
      }
    __builtin_amdgcn_s_setprio(0);
    __builtin_amdgcn_s_barrier();

    // ---- phase 4: stage (t+2).Bh1; counted vmcnt; q3 ----
    if (t + 2 < NT) {
      stB(buf, 1, t + 2);
      asm volatile("s_waitcnt vmcnt(4)" ::: "memory");
    } else {
      asm volatile("s_waitcnt vmcnt(0)" ::: "memory");
    }
    __builtin_amdgcn_s_barrier();
    __builtin_amdgcn_s_setprio(1);
#pragma unroll
    for (int mm = 0; mm < 4; ++mm)
#pragma unroll
      for (int nn = 0; nn < 2; ++nn) {
        acc[4 + mm][nn] = __builtin_amdgcn_mfma_f32_16x16x32_f16(a[mm][0], b01[nn][0], acc[4 + mm][nn], 0, 0, 0);
        acc[4 + mm][nn] = __builtin_amdgcn_mfma_f32_16x16x32_f16(a[mm][1], b01[nn][1], acc[4 + mm][nn], 0, 0, 0);
      }
    __builtin_amdgcn_s_setprio(0);
    __builtin_amdgcn_s_barrier();
  }

  // epilogue: C/D layout col=lane&15, row=(lane>>4)*4+reg
  const int crow = bm * 256 + wr * 128 + kgrp * 4;
  const int ccol = bn * 256 + wc * 64 + fr;
#pragma unroll
  for (int n = 0; n < 4; ++n) {
    const int col = ccol + n * 16;
    const float bv = bias[col];
#pragma unroll
    for (int m = 0; m < 8; ++m) {
      const int row0 = crow + m * 16;
#pragma unroll
      for (int r = 0; r < 4; ++r)
        C[(size_t)(row0 + r) * ldc + col] = acc[m][n][r] + bv;
    }
  }
}

// ---------------- launch ----------------
extern "C" void kernel_launch(void* const* d_in, const int* in_sizes, int n_in,
                              void* d_out, int out_size, void* d_ws, size_t ws_size,
                              hipStream_t stream) {
  const float* x    = (const float*)d_in[0];
  const int*   qv   = (const int*)d_in[1];
  const float* qs   = (const float*)d_in[2];
  const int*   lv   = (const int*)d_in[3];
  const float* ls   = (const float*)d_in[4];
  const int*   rv   = (const int*)d_in[5];
  const float* rs   = (const float*)d_in[6];
  const float* bias = (const float*)d_in[7];

  int M = in_sizes[0] / D_IN;   // 8192

  char* ws = (char*)d_ws;
  _Float16* Xcat = (_Float16*)ws;                                   // [M][KCAT]
  _Float16* Wcat = (_Float16*)(ws + (size_t)M * KCAT * 2);          // [D_OUT][KCAT]
  _Float16* Rh   = (_Float16*)(ws + (size_t)(M + D_OUT) * KCAT * 2);// [RANK][D_IN]

  k_dequant_w<<<dim3((KCAT / 4 + 255) / 256, D_OUT), 256, 0, stream>>>(qv, qs, lv, ls, Wcat);
  k_dequant_r<<<dim3(D_IN / 4 / 256, RANK), 256, 0, stream>>>(rv, rs, Rh);
  int total4 = M * (D_IN / 4);
  k_convert_x<<<(total4 + 255) / 256, 256, 0, stream>>>(x, Xcat, total4);

  // xr = Xcat[:, :4096] @ Rh^T  -> f16 into Xcat[:, 4096:4352]
  k_gemm_bt<128, 64, 4, 2, true, false><<<(M / 128) * (RANK / 64), 256, 0, stream>>>(
      Xcat, KCAT, Rh, D_IN, (void*)(Xcat + D_IN), KCAT, nullptr, D_IN, RANK / 64);

  // out = Xcat @ Wcat^T + bias   (K = 4352, 8-phase 256^2 kernel)
  k_gemm256<<<(M / 256) * (D_OUT / 256), 512, 0, stream>>>(
      Xcat, KCAT, Wcat, KCAT, (float*)d_out, D_OUT, bias, KCAT, D_OUT / 256);
}

// Round 3
// 569.434 us; speedup vs baseline: 1.2957x; 1.0481x over previous
//
#include <hip/hip_runtime.h>

#define D_IN  4096
#define D_OUT 4096
#define RANK  256
#define KCAT  (D_IN + RANK)   // 4352

typedef _Float16 h4 __attribute__((ext_vector_type(4)));
typedef _Float16 h8 __attribute__((ext_vector_type(8)));
typedef float    f4 __attribute__((ext_vector_type(4)));

__device__ __forceinline__ void gload16(const void* g, void* l) {
  __builtin_amdgcn_global_load_lds(
      (const __attribute__((address_space(1))) void*)g,
      (__attribute__((address_space(3))) void*)l, 16, 0, 0);
}

// ---------------- prologue: dequant + pack ----------------

__global__ __launch_bounds__(256) void k_dequant_w(
    const int* __restrict__ qv, const float* __restrict__ qs,
    const int* __restrict__ lv, const float* __restrict__ ls,
    _Float16* __restrict__ W) {
  int row = blockIdx.y;
  int c4 = blockIdx.x * 256 + threadIdx.x;    // quad index, 0..1087
  if (c4 >= KCAT / 4) return;
  int col = c4 * 4;
  int4 v; float s;
  if (col < D_IN) {
    v = *(const int4*)(qv + (size_t)row * D_IN + col);
    s = qs[row * (D_IN / 128) + (col >> 7)];
  } else {
    int lc = col - D_IN;
    v = *(const int4*)(lv + (size_t)row * RANK + lc);
    s = ls[row * (RANK / 128) + (lc >> 7)];
  }
  h4 h;
  h[0] = (_Float16)((float)v.x * s);
  h[1] = (_Float16)((float)v.y * s);
  h[2] = (_Float16)((float)v.z * s);
  h[3] = (_Float16)((float)v.w * s);
  *(h4*)(W + (size_t)row * KCAT + col) = h;
}

__global__ __launch_bounds__(256) void k_dequant_r(
    const int* __restrict__ rv, const float* __restrict__ rs,
    _Float16* __restrict__ R) {
  int row = blockIdx.y;
  int c4 = blockIdx.x * 256 + threadIdx.x;    // 0..1023
  int col = c4 * 4;
  int4 v = *(const int4*)(rv + (size_t)row * D_IN + col);
  float s = rs[row * (D_IN / 128) + (col >> 7)];
  h4 h;
  h[0] = (_Float16)((float)v.x * s);
  h[1] = (_Float16)((float)v.y * s);
  h[2] = (_Float16)((float)v.z * s);
  h[3] = (_Float16)((float)v.w * s);
  *(h4*)(R + (size_t)row * D_IN + col) = h;
}

__global__ __launch_bounds__(256) void k_convert_x(
    const float* __restrict__ x, _Float16* __restrict__ X, int total4) {
  int i = blockIdx.x * 256 + threadIdx.x;
  if (i >= total4) return;
  f4 v = *(const f4*)(x + (size_t)i * 4);
  int row = i >> 10;           // D_IN/4 = 1024 quads per row
  int c4  = i & 1023;
  h4 h;
  h[0] = (_Float16)v[0]; h[1] = (_Float16)v[1];
  h[2] = (_Float16)v[2]; h[3] = (_Float16)v[3];
  *(h4*)(X + (size_t)row * KCAT + c4 * 4) = h;
}

// ---------------- small GEMM (xr path): m97 structure, 64^2 ----------------
template<int BM, int BN, int MF, int NF, bool OUT_F16, bool ADD_BIAS>
__global__ __launch_bounds__(256) void k_gemm_bt(
    const _Float16* __restrict__ A, int lda,
    const _Float16* __restrict__ B, int ldb,
    void* __restrict__ Cv, int ldc,
    const float* __restrict__ bias,
    int K, int grid_n) {
  constexpr int WM = MF * 16, WN = NF * 16;
  __shared__ _Float16 As[BM][32];
  __shared__ _Float16 Bs[BN][32];

  int bid = blockIdx.x;
  { int q = gridDim.x >> 3; bid = (bid & 7) * q + (bid >> 3); }
  int bm = bid / grid_n, bn = bid % grid_n;

  int tid  = threadIdx.x;
  int lane = tid & 63, wave = tid >> 6;
  int wr = wave >> 1, wc = wave & 1;

  int trow = tid >> 2;
  int tcol = (tid & 3) * 8;
  const _Float16* ga = A + (size_t)(bm * BM + trow) * lda + tcol;
  const _Float16* gb = B + (size_t)(bn * BN + trow) * ldb + tcol;

  f4 acc[MF][NF] = {};

  int fr = lane & 15;
  int fk = (lane >> 4) * 8;

  for (int k0 = 0; k0 < K; k0 += 32) {
#pragma unroll
    for (int p = 0; p < BM / 64; ++p)
      gload16(ga + (size_t)p * 64 * lda + k0, &As[p * 64 + trow][tcol]);
#pragma unroll
    for (int p = 0; p < BN / 64; ++p)
      gload16(gb + (size_t)p * 64 * ldb + k0, &Bs[p * 64 + trow][tcol]);
    __syncthreads();

    h8 a[MF], b[NF];
#pragma unroll
    for (int m = 0; m < MF; ++m)
      a[m] = *(const h8*)&As[wr * WM + m * 16 + fr][fk];
#pragma unroll
    for (int n = 0; n < NF; ++n)
      b[n] = *(const h8*)&Bs[wc * WN + n * 16 + fr][fk];
#pragma unroll
    for (int m = 0; m < MF; ++m)
#pragma unroll
      for (int n = 0; n < NF; ++n)
        acc[m][n] = __builtin_amdgcn_mfma_f32_16x16x32_f16(a[m], b[n], acc[m][n], 0, 0, 0);
    __syncthreads();
  }

  int cr = (lane >> 4) * 4;
  int cc = lane & 15;
#pragma unroll
  for (int m = 0; m < MF; ++m) {
#pragma unroll
    for (int n = 0; n < NF; ++n) {
      int col = bn * BN + wc * WN + n * 16 + cc;
      float bv = ADD_BIAS ? bias[col] : 0.f;
#pragma unroll
      for (int r = 0; r < 4; ++r) {
        int row = bm * BM + wr * WM + m * 16 + cr + r;
        float val = acc[m][n][r] + bv;
        if (OUT_F16) ((_Float16*)Cv)[(size_t)row * ldc + col] = (_Float16)val;
        else         ((float*)Cv)[(size_t)row * ldc + col]    = val;
      }
    }
  }
}

// ---------------- main GEMM: 256x256 8-phase, pipelined ds_reads ----------------
// C[M][N] = A[M][KCAT] * B[N][KCAT]^T + bias.  BK=64, 8 waves (2Mx4N), 128 KiB LDS.
// Read issue points (tile t): [A03,B01] at p4 of t-1; B23 at p1; A47 at p2.
// Quadrants: q0=A03*B01, q1=A03*B23, q2=A47*B01, q3=A47*B23 (last-use ordering
// guarantees single-named fragment registers are dead before re-issue).
// Waits: q0 lgkm(4), q1 lgkm(8), q2 lgkm(0), q3 none; vmcnt(4) once per tile.
__global__ __launch_bounds__(512, 2) void k_gemm256(
    const _Float16* __restrict__ A,
    const _Float16* __restrict__ B,
    float* __restrict__ C,
    const float* __restrict__ bias) {
  constexpr int LDA = KCAT, LDB = KCAT, LDC = D_OUT;
  constexpr int NT = KCAT / 64;          // 68 (even; loop is 2x-unrolled)
  constexpr int GRID_N = D_OUT / 256;
  __shared__ _Float16 smem[2 * 4 * 8192];   // 131072 B

  int bid = blockIdx.x;
  { int q = gridDim.x >> 3; bid = (bid & 7) * q + (bid >> 3); }  // XCD swizzle
  const int bm = bid / GRID_N, bn = bid % GRID_N;

  const int tid  = threadIdx.x;
  const int lane = tid & 63, wave = tid >> 6;
  const int wr = wave >> 2;          // 0..1  (M half)
  const int wc = wave & 3;           // 0..3  (N quarter)

  const int fr   = lane & 15;        // fragment row
  const int kgrp = lane >> 4;        // 0..3
  const int xorv = fr & 7;
  const int seg0 = ((0 | kgrp) ^ xorv) * 8;
  const int seg1 = ((4 | kgrp) ^ xorv) * 8;

  // staging map: thread -> row tid/8, seg (tid&7)^(row&7); LDS linear tid*16B
  const int srow = tid >> 3;
  const int scol = ((tid & 7) ^ (srow & 7)) * 8;
  const _Float16* gA = A + (size_t)(bm * 256 + srow) * LDA + scol;
  const _Float16* gB = B + (size_t)(bn * 256 + srow) * LDB + scol;

  f4 acc[8][4] = {};
  h8 a_lo[4][2], a_hi[4][2], b01[2][2], b23[2][2];

  auto stA = [&](int buf, int h, int t) {
    const _Float16* g = gA + (size_t)h * 128 * LDA + t * 64;
    _Float16* l = smem + (buf * 4 + h) * 8192 + tid * 8;
    gload16(g, l);
    gload16(g + (size_t)64 * LDA, l + 4096);
  };
  auto stB = [&](int buf, int h, int t) {
    const _Float16* g = gB + (size_t)h * 128 * LDB + t * 64;
    _Float16* l = smem + (buf * 4 + 2 + h) * 8192 + tid * 8;
    gload16(g, l);
    gload16(g + (size_t)64 * LDB, l + 4096);
  };
  auto rdA = [&](h8 (&dst)[4][2], int buf, int mbase) {
    const _Float16* p = smem + (buf * 4 + wr) * 8192 + fr * 64;
#pragma unroll
    for (int mm = 0; mm < 4; ++mm) {
      dst[mm][0] = *(const h8*)(p + (mbase + mm) * 1024 + seg0);
      dst[mm][1] = *(const h8*)(p + (mbase + mm) * 1024 + seg1);
    }
  };
  auto rdB = [&](h8 (&dst)[2][2], int buf, int nbase) {
    const _Float16* p = smem + (buf * 4 + 2 + (wc >> 1)) * 8192
                      + ((wc & 1) * 64 + fr) * 64;
#pragma unroll
    for (int nn = 0; nn < 2; ++nn) {
      dst[nn][0] = *(const h8*)(p + (nbase + nn) * 1024 + seg0);
      dst[nn][1] = *(const h8*)(p + (nbase + nn) * 1024 + seg1);
    }
  };

#define QUAD(AF, BF, MO, NO)                                                   \
  __builtin_amdgcn_s_setprio(1);                                               \
  _Pragma("unroll")                                                            \
  for (int mm = 0; mm < 4; ++mm)                                               \
    _Pragma("unroll")                                                          \
    for (int nn = 0; nn < 2; ++nn) {                                           \
      acc[MO + mm][NO + nn] = __builtin_amdgcn_mfma_f32_16x16x32_f16(          \
          AF[mm][0], BF[nn][0], acc[MO + mm][NO + nn], 0, 0, 0);               \
      acc[MO + mm][NO + nn] = __builtin_amdgcn_mfma_f32_16x16x32_f16(          \
          AF[mm][1], BF[nn][1], acc[MO + mm][NO + nn], 0, 0, 0);               \
    }                                                                          \
  __builtin_amdgcn_s_setprio(0);

#define BAR() __builtin_amdgcn_s_barrier()
#define LGKM(N) asm volatile("s_waitcnt lgkmcnt(" #N ")" ::: "memory")
#define VMC(N)  asm volatile("s_waitcnt vmcnt(" #N ")" ::: "memory")

  // ---- prologue: stage t0 fully + t1's B halves ----
  stA(0, 0, 0); stA(0, 1, 0); stB(0, 0, 0); stB(0, 1, 0);
  stB(1, 0, 1); stB(1, 1, 1);
  VMC(4);                      // retire t0's 8 loads; t1-B stays in flight
  BAR();
  rdA(a_lo, 0, 0); rdB(b01, 0, 0);   // tile-0 [A03,B01]

  auto tile = [&](int t, int buf) {
    const int nbuf = buf ^ 1;
    // ---- p1: issue B23; stage (t+1).Ah0; q0 ----
    rdB(b23, buf, 2);
    if (t + 1 < NT) stA(nbuf, 0, t + 1);
    BAR();
    LGKM(4);                   // A03,B01 done; B23 may stay out
    QUAD(a_lo, b01, 0, 0);
    BAR();
    // ---- p2: issue A47; stage (t+1).Ah1; q1 ----
    rdA(a_hi, buf, 4);
    if (t + 1 < NT) stA(nbuf, 1, t + 1);
    BAR();
    LGKM(8);                   // B23 done; A47 may stay out
    QUAD(a_lo, b23, 0, 2);
    BAR();
    // ---- p3: stage (t+2).Bh0; q2 ----
    if (t + 2 < NT) stB(buf, 0, t + 2);
    BAR();
    LGKM(0);                   // A47 done
    QUAD(a_hi, b01, 4, 0);
    BAR();
    // ---- p4: stage (t+2).Bh1; counted vmcnt; prefetch next [A03,B01]; q3 ----
    if (t + 2 < NT) {
      stB(buf, 1, t + 2);
      VMC(4);                  // retire all of tile t+1's staged data
    } else {
      VMC(0);
    }
    BAR();
    if (t + 1 < NT) { rdA(a_lo, nbuf, 0); rdB(b01, nbuf, 0); }
    QUAD(a_hi, b23, 4, 2);     // operands already waited at q2's lgkm(0)
    BAR();
  };

  for (int tt = 0; tt < NT; tt += 2) {   // NT even: constant buf per call
    tile(tt, 0);
    tile(tt + 1, 1);
  }

  // epilogue: C/D layout col=lane&15, row=(lane>>4)*4+reg
  const int crow = bm * 256 + wr * 128 + kgrp * 4;
  const int ccol = bn * 256 + wc * 64 + fr;
#pragma unroll
  for (int n = 0; n < 4; ++n) {
    const int col = ccol + n * 16;
    const float bv = bias[col];
#pragma unroll
    for (int m = 0; m < 8; ++m) {
      const int row0 = crow + m * 16;
#pragma unroll
      for (int r = 0; r < 4; ++r)
        C[(size_t)(row0 + r) * LDC + col] = acc[m][n][r] + bv;
    }
  }
#undef QUAD
#undef BAR
#undef LGKM
#undef VMC
}

// ---------------- launch ----------------
extern "C" void kernel_launch(void* const* d_in, const int* in_sizes, int n_in,
                              void* d_out, int out_size, void* d_ws, size_t ws_size,
                              hipStream_t stream) {
  const float* x    = (const float*)d_in[0];
  const int*   qv   = (const int*)d_in[1];
  const float* qs   = (const float*)d_in[2];
  const int*   lv   = (const int*)d_in[3];
  const float* ls   = (const float*)d_in[4];
  const int*   rv   = (const int*)d_in[5];
  const float* rs   = (const float*)d_in[6];
  const float* bias = (const float*)d_in[7];

  int M = in_sizes[0] / D_IN;   // 8192

  char* ws = (char*)d_ws;
  _Float16* Xcat = (_Float16*)ws;                                   // [M][KCAT]
  _Float16* Wcat = (_Float16*)(ws + (size_t)M * KCAT * 2);          // [D_OUT][KCAT]
  _Float16* Rh   = (_Float16*)(ws + (size_t)(M + D_OUT) * KCAT * 2);// [RANK][D_IN]

  k_dequant_w<<<dim3((KCAT / 4 + 255) / 256, D_OUT), 256, 0, stream>>>(qv, qs, lv, ls, Wcat);
  k_dequant_r<<<dim3(D_IN / 4 / 256, RANK), 256, 0, stream>>>(rv, rs, Rh);
  int total4 = M * (D_IN / 4);
  k_convert_x<<<(total4 + 255) / 256, 256, 0, stream>>>(x, Xcat, total4);

  // xr = Xcat[:, :4096] @ Rh^T  -> f16 into Xcat[:, 4096:4352]  (round-1 64^2 config)
  k_gemm_bt<64, 64, 2, 2, true, false><<<(M / 64) * (RANK / 64), 256, 0, stream>>>(
      Xcat, KCAT, Rh, D_IN, (void*)(Xcat + D_IN), KCAT, nullptr, D_IN, RANK / 64);

  // out = Xcat @ Wcat^T + bias   (K = 4352, pipelined 256^2 kernel)
  k_gemm256<<<(M / 256) * (D_OUT / 256), 512, 0, stream>>>(
      Xcat, Wcat, (float*)d_out, bias);
}